// Round 8
// baseline (610.399 us; speedup 1.0000x reference)
//
#include <hip/hip_runtime.h>
#include <cstdint>
#include <cstddef>

// ---------------------------------------------------------------------------
// TensoSDF shape renderer: tri-plane sample + embed -> MLP(129->256->129)
// R9: Morton spatial sort -> gather locality.
//  Evidence chain: FETCH pinned ~352MB = pl_t gather lines missing LLC ~50%
//  (R7 NT-store test proved the write stream can't be kept out of the
//  memory-side LLC; reuse distance of random points > LLC). Fix reuse
//  distance at the SOURCE: counting-sort points by 15-bit Morton cell
//  (32^3); a 64-pt block then touches a few-KB plane neighborhood ->
//  L2-resident gathers. Output becomes per-row scatter (516B contiguous
//  rows, 2x256B coalesced stores + 1 dword; ~67MB boundary RMW, normal
//  stores so L2 merges).
// Keeps: NCP=40 padded planes/lines, task-split coalesced gather (R8),
//  N-slice layer-2 (R8), k-permuted w1/w2, LDS union, bounds(256,3).
// ---------------------------------------------------------------------------

using half2v  = __attribute__((ext_vector_type(2))) _Float16;
using half4   = __attribute__((ext_vector_type(4))) _Float16;
using half8   = __attribute__((ext_vector_type(8))) _Float16;
using floatx4 = __attribute__((ext_vector_type(4))) float;

#define NPTS    524288
#define GRES    300
#define NCOMP   36
#define NCP     40
#define SDFD    256
#define IN_CH   129
#define OUT_CH  129
#define TILE_M  64
#define S_INL   168     // mlp_in LDS stride in halfs
#define S_OUT   136     // out-stage LDS stride in floats
#define NCELL   32768   // 32^3 Morton cells

// workspace layout (bytes), all 16B aligned
#define OFF_W1S 0
#define SZ_W1S  (5*4*256*8*2)               // 81920 : w1 swizzled f16
#define OFF_W2S (OFF_W1S + SZ_W1S)
#define SZ_W2S  (8*4*144*8*2)               // 73728 : w2 swizzled f16
#define OFF_LT  (OFF_W2S + SZ_W2S)
#define SZ_LT   (3*GRES*NCP*2)              // 72000 : lines ch-last padded f16
#define OFF_HIST (OFF_LT + SZ_LT + 64)      // pad to 16B
#define SZ_HIST (NCELL*4)                   // 131072
#define OFF_CUR (OFF_HIST + SZ_HIST)
#define SZ_CUR  (NCELL*4)                   // 131072
#define OFF_PERM (OFF_CUR + SZ_CUR)
#define SZ_PERM (NPTS*4)                    // 2MB
#define OFF_PLT (OFF_PERM + SZ_PERM)
#define SZ_PLT  ((size_t)3*GRES*GRES*NCP*2) // 21.6MB: planes ch-last padded f16
#define NEED_FAST ((size_t)OFF_PLT + SZ_PLT)

// ---- prep kernels ---------------------------------------------------------

__global__ void prep_planes_k(const float* __restrict__ planes, _Float16* __restrict__ pl_t) {
    int idx = blockIdx.x * 256 + threadIdx.x;           // (m*300+y)*300+x
    if (idx >= 3 * GRES * GRES) return;
    int x = idx % GRES; int t = idx / GRES; int y = t % GRES; int m = t / GRES;
    _Float16* dst = pl_t + (size_t)idx * NCP;
    const float* src = planes + (size_t)m * NCOMP * GRES * GRES + (size_t)y * GRES + x;
    #pragma unroll
    for (int j = 0; j < 5; ++j) {
        half8 o;
        #pragma unroll
        for (int e = 0; e < 8; ++e) {
            int c = j * 8 + e;
            o[e] = (c < NCOMP) ? (_Float16)src[(size_t)c * GRES * GRES] : (_Float16)0.f;
        }
        *(half8*)(dst + j * 8) = o;
    }
}

#define NB_W1 ((5*4*256*8 + 255)/256)      // 160
#define NB_W2 ((8*4*144*8 + 255)/256)      // 144
#define NB_L  ((3*GRES + 255)/256)         // 4
__global__ void prep_small_k(const float* __restrict__ w1, const float* __restrict__ w2,
                             const float* __restrict__ lines,
                             _Float16* __restrict__ w1s, _Float16* __restrict__ w2s,
                             _Float16* __restrict__ l_t) {
    int b = blockIdx.x;
    if (b < NB_W1) {
        int t = b * 256 + threadIdx.x;                   // < 40960 exactly
        int j = t & 7; int n = (t >> 3) & 255; int q = t >> 11;
        int k = q * 8 + j;                               // 0..159
        float v = 0.f;
        if (k < 120) {
            int m = k / 40, c = k % 40;
            if (c < NCOMP) v = w1[n * IN_CH + 21 + m * NCOMP + c];
        } else if (k < 141) {
            v = w1[n * IN_CH + (k - 120)];
        }
        w1s[t] = (_Float16)v;
    } else if (b < NB_W1 + NB_W2) {
        int t = (b - NB_W1) * 256 + threadIdx.x;
        if (t >= 8*4*144*8) return;
        int j = t & 7; int r = t >> 3; int n = r % 144; int q = r / 144;
        int k = q * 8 + j;                               // 0..255
        float v = (n < OUT_CH) ? w2[n * SDFD + k] : 0.f;
        w2s[t] = (_Float16)v;
    } else {
        int idx = (b - NB_W1 - NB_W2) * 256 + threadIdx.x;   // m*300+z
        if (idx >= 3 * GRES) return;
        int z = idx % GRES; int m = idx / GRES;
        _Float16* dst = l_t + (size_t)idx * NCP;
        const float* src = lines + ((size_t)m * NCOMP) * GRES + z;
        #pragma unroll
        for (int c = 0; c < NCOMP; ++c) dst[c] = (_Float16)src[(size_t)c * GRES];
        dst[36] = dst[37] = dst[38] = dst[39] = (_Float16)0.f;
    }
}

// ---- Morton sort kernels --------------------------------------------------

__device__ __forceinline__ uint32_t spread5(uint32_t a) {
    a &= 31u;
    a = (a | (a << 8)) & 0x100Fu;
    a = (a | (a << 4)) & 0x10C3u;
    a = (a | (a << 2)) & 0x1249u;
    return a;
}

__device__ __forceinline__ uint32_t cell_code(float X, float Y, float Z) {
    int cx = (int)((X + 1.f) * 16.f); cx = cx < 0 ? 0 : (cx > 31 ? 31 : cx);
    int cy = (int)((Y + 1.f) * 16.f); cy = cy < 0 ? 0 : (cy > 31 ? 31 : cy);
    int cz = (int)((Z + 1.f) * 16.f); cz = cz < 0 ? 0 : (cz > 31 ? 31 : cz);
    return spread5((uint32_t)cx) | (spread5((uint32_t)cy) << 1) | (spread5((uint32_t)cz) << 2);
}

__global__ void zero_k(uint32_t* __restrict__ p) {
    p[blockIdx.x * 256 + threadIdx.x] = 0u;             // grid = NCELL/256
}

__global__ void hist_k(const float* __restrict__ xyz, uint32_t* __restrict__ hist) {
    int i = blockIdx.x * 256 + threadIdx.x;             // grid = NPTS/256
    atomicAdd(&hist[cell_code(xyz[i*3], xyz[i*3+1], xyz[i*3+2])], 1u);
}

__global__ void scan_k(const uint32_t* __restrict__ hist, uint32_t* __restrict__ cur) {
    __shared__ uint32_t part[256];
    const int t = threadIdx.x;
    uint32_t s = 0;
    for (int i = 0; i < NCELL/256; ++i) s += hist[t * (NCELL/256) + i];
    part[t] = s;
    __syncthreads();
    if (t == 0) {
        uint32_t a = 0;
        for (int i = 0; i < 256; ++i) { uint32_t v = part[i]; part[i] = a; a += v; }
    }
    __syncthreads();
    uint32_t a = part[t];
    for (int i = 0; i < NCELL/256; ++i) {
        uint32_t v = hist[t * (NCELL/256) + i];
        cur[t * (NCELL/256) + i] = a;
        a += v;
    }
}

__global__ void scat_k(const float* __restrict__ xyz, uint32_t* __restrict__ cur,
                       uint32_t* __restrict__ perm) {
    int i = blockIdx.x * 256 + threadIdx.x;             // grid = NPTS/256
    uint32_t idx = atomicAdd(&cur[cell_code(xyz[i*3], xyz[i*3+1], xyz[i*3+2])], 1u);
    perm[idx] = (uint32_t)i;
}

// ---- device helpers -------------------------------------------------------

__device__ __forceinline__ float softplus100(float z) {
    return fmaxf(z, 0.f) + __logf(1.f + __expf(-fabsf(z)));
}

__device__ __forceinline__ void plane_coords(int m, float X, float Y, float Z,
                                             int& x0, int& y0, int& z0,
                                             float& tx, float& ty, float& tz) {
    const float px = (m == 2) ? Y : X;
    const float py = (m == 0) ? Y : Z;
    const float pz = (m == 0) ? Z : ((m == 1) ? Y : X);
    float fx = (px + 1.f) * 0.5f * 299.f;
    float fy = (py + 1.f) * 0.5f * 299.f;
    float fz = (pz + 1.f) * 0.5f * 299.f;
    x0 = (int)floorf(fx); x0 = x0 < 0 ? 0 : (x0 > 298 ? 298 : x0);
    y0 = (int)floorf(fy); y0 = y0 < 0 ? 0 : (y0 > 298 ? 298 : y0);
    z0 = (int)floorf(fz); z0 = z0 < 0 ? 0 : (z0 > 298 ? 298 : z0);
    tx = fx - (float)x0; ty = fy - (float)y0; tz = fz - (float)z0;
}

// embed -> chunks c16=15..19 (k=120..159); zeros beyond k=140
__device__ __forceinline__ void embed_chunks(float X, float Y, float Z, half8 e[5]) {
    const float v3[3] = {X, Y, Z};
    _Float16 s[3][3], c[3][3];
    #pragma unroll
    for (int d = 0; d < 3; ++d) {
        float fm = 1.f;
        #pragma unroll
        for (int q = 0; q < 3; ++q) {
            const float a = v3[d] * fm;
            s[d][q] = (_Float16)__sinf(a);
            c[d][q] = (_Float16)__cosf(a);
            fm *= 2.f;
        }
    }
    const _Float16 z0 = (_Float16)0.f;
    e[0] = (half8){(_Float16)X, (_Float16)Y, (_Float16)Z, s[0][0], s[0][1], s[0][2], s[1][0], s[1][1]};
    e[1] = (half8){s[1][2], s[2][0], s[2][1], s[2][2], c[0][0], c[0][1], c[0][2], c[1][0]};
    e[2] = (half8){c[1][1], c[1][2], c[2][0], c[2][1], c[2][2], z0, z0, z0};
    e[3] = (half8){z0,z0,z0,z0,z0,z0,z0,z0};
    e[4] = (half8){z0,z0,z0,z0,z0,z0,z0,z0};
}

__device__ __forceinline__ half8 splat8(_Float16 v) {
    return (half8){v, v, v, v, v, v, v, v};
}

// ---- fused kernel ---------------------------------------------------------
// LDS: 34816B union + 256B perm.
//   A (phase1/layer1): mlp_in [64][S_INL=168] f16, 21504B; xyz stage f32[64][3]
//     at byte 21504 (dead after phase1)
//   B (epilogue1/layer2): h [64][256] f16 XOR-swz (row&7)<<3, 32768B
//   C (epilogue2): out stage [64][S_OUT=136] f32, 34816B
// Points processed in Morton-sorted order via perm[]; output scattered per row.

template <int FASTMODE>
__global__ __launch_bounds__(256, 3)
void tsdf_fused40_k(const float* __restrict__ xyz,
                    const float* __restrict__ planes, const float* __restrict__ lines,
                    const _Float16* __restrict__ pl_t, const _Float16* __restrict__ l_t,
                    const _Float16* __restrict__ w1s, const _Float16* __restrict__ w2s,
                    const float* __restrict__ b1, const float* __restrict__ b2,
                    const uint32_t* __restrict__ perm,
                    float* __restrict__ out)
{
    __shared__ _Float16 lds_u[TILE_M * 272];           // 34816 B union
    __shared__ uint32_t perm_s[TILE_M];                // 256 B
    _Float16* mlp_lds = lds_u;                         // [64][S_INL]
    _Float16* h_lds   = lds_u;                         // [64][256] swz
    float*    xyz_s   = (float*)&lds_u[10752];         // [64][3] f32 @byte 21504
    const int tid = threadIdx.x, blk = blockIdx.x;

    // ---------------- phase 0: stage perm + xyz -----------------------------
    if (tid < TILE_M)
        perm_s[tid] = perm ? perm[(size_t)blk * TILE_M + tid]
                           : (uint32_t)(blk * TILE_M + tid);
    __syncthreads();
    if (tid < TILE_M * 3) {
        const int pt = tid / 3, c = tid - pt * 3;
        xyz_s[tid] = xyz[(size_t)perm_s[pt] * 3 + c];
    }
    __syncthreads();

    // ---------------- phase 1: sampling + embed into LDS -------------------
    {
        const int task = tid & 15;                     // 0..14 gather, 15 embed
        const int pb4  = (tid >> 4) * 4;               // first of 4 points
        const int m    = task / 5;                     // plane (3 if embed)
        const int j    = task - m * 5;                 // chunk within plane
        #pragma unroll
        for (int g = 0; g < 4; ++g) {
            const int p = pb4 + g;
            const float X = xyz_s[p * 3 + 0];
            const float Y = xyz_s[p * 3 + 1];
            const float Z = xyz_s[p * 3 + 2];
            if (task < 15) {
                int x0, y0, z0; float tx, ty, tz;
                plane_coords(m, X, Y, Z, x0, y0, z0, tx, ty, tz);
                if (FASTMODE) {
                    const half8 W00 = splat8((_Float16)((1.f - tx) * (1.f - ty)));
                    const half8 W01 = splat8((_Float16)(tx * (1.f - ty)));
                    const half8 W10 = splat8((_Float16)((1.f - tx) * ty));
                    const half8 W11 = splat8((_Float16)(tx * ty));
                    const half8 WL0 = splat8((_Float16)(1.f - tz));
                    const half8 WL1 = splat8((_Float16)tz);
                    const _Float16* r0 = pl_t + ((size_t)(m * GRES + y0) * GRES + x0) * NCP + 8 * j;
                    const _Float16* r1 = r0 + (size_t)GRES * NCP;
                    const _Float16* lb = l_t + (size_t)(m * GRES + z0) * NCP + 8 * j;
                    const half8 v00 = *(const half8*)(r0);
                    const half8 v01 = *(const half8*)(r0 + NCP);
                    const half8 v10 = *(const half8*)(r1);
                    const half8 v11 = *(const half8*)(r1 + NCP);
                    const half8 l0  = *(const half8*)(lb);
                    const half8 l1  = *(const half8*)(lb + NCP);
                    const half8 pf = v00 * W00 + v01 * W01 + v10 * W10 + v11 * W11;
                    const half8 lf = l0 * WL0 + l1 * WL1;
                    *(half8*)&mlp_lds[p * S_INL + task * 8] = pf * lf;
                } else {
                    const float w00 = (1.f - tx) * (1.f - ty), w01 = tx * (1.f - ty);
                    const float w10 = (1.f - tx) * ty,         w11 = tx * ty;
                    const float lw0 = 1.f - tz, lw1 = tz;
                    half8 f;
                    #pragma unroll
                    for (int e = 0; e < 8; ++e) {
                        const int c = j * 8 + e;
                        float v = 0.f;
                        if (c < NCOMP) {
                            const float* pc = planes + ((size_t)(m * NCOMP + c) * GRES + y0) * GRES + x0;
                            const float* lc = lines + ((size_t)m * NCOMP + c) * GRES + z0;
                            const float pfv = pc[0] * w00 + pc[1] * w01 + pc[GRES] * w10 + pc[GRES + 1] * w11;
                            v = pfv * (lc[0] * lw0 + lc[1] * lw1);
                        }
                        f[e] = (_Float16)v;
                    }
                    *(half8*)&mlp_lds[p * S_INL + task * 8] = f;
                }
            } else {
                half8 e[5];
                embed_chunks(X, Y, Z, e);
                #pragma unroll
                for (int jj = 0; jj < 5; ++jj)
                    *(half8*)&mlp_lds[p * S_INL + (15 + jj) * 8] = e[jj];
            }
        }
    }
    __syncthreads();

    const int lane = tid & 63, wv = tid >> 6, l15 = lane & 15, quad = lane >> 4;

    // ---------------- layer 1: [64x160] @ [160x256] -> h -------------------
    floatx4 acc1[4][4];
    #pragma unroll
    for (int mt = 0; mt < 4; ++mt)
        #pragma unroll
        for (int nt = 0; nt < 4; ++nt)
            acc1[mt][nt] = (floatx4){0.f, 0.f, 0.f, 0.f};

    #pragma unroll
    for (int s = 0; s < 5; ++s) {
        half8 a[4], b[4];
        #pragma unroll
        for (int mt = 0; mt < 4; ++mt)
            a[mt] = *(const half8*)&mlp_lds[(mt * 16 + l15) * S_INL + s * 32 + quad * 8];
        #pragma unroll
        for (int nt = 0; nt < 4; ++nt)
            b[nt] = *(const half8*)(w1s + ((size_t)((s * 4 + quad) * 256) + wv * 64 + nt * 16 + l15) * 8);
        #pragma unroll
        for (int mt = 0; mt < 4; ++mt)
            #pragma unroll
            for (int nt = 0; nt < 4; ++nt)
                acc1[mt][nt] = __builtin_amdgcn_mfma_f32_16x16x32_f16(a[mt], b[nt], acc1[mt][nt], 0, 0, 0);
    }
    __syncthreads();   // mlp_lds reads done; union -> h

    // epilogue 1: softplus(100z)/100, write h (f16) to swizzled LDS
    #pragma unroll
    for (int nt = 0; nt < 4; ++nt) {
        const int n = wv * 64 + nt * 16 + l15;
        const float bias = b1[n];
        #pragma unroll
        for (int mt = 0; mt < 4; ++mt) {
            #pragma unroll
            for (int r = 0; r < 4; ++r) {
                const int rowh = mt * 16 + quad * 4 + r;
                const float z = 100.f * (acc1[mt][nt][r] + bias);
                h_lds[(rowh * 256 + n) ^ ((rowh & 7) << 3)] = (_Float16)(softplus100(z) * 0.01f);
            }
        }
    }
    __syncthreads();

    // ---------------- layer 2: [64x256] @ [256x144] -> out -----------------
    // N-slice ownership: wave w owns col-tiles {w, w+4, (8 for w==0)}.
    const int NTL = (wv == 0) ? 3 : 2;
    floatx4 acc2[4][3];
    #pragma unroll
    for (int mt = 0; mt < 4; ++mt)
        #pragma unroll
        for (int ntl = 0; ntl < 3; ++ntl)
            acc2[mt][ntl] = (floatx4){0.f, 0.f, 0.f, 0.f};

    #pragma unroll
    for (int s = 0; s < 8; ++s) {
        half8 a[4];
        #pragma unroll
        for (int mt = 0; mt < 4; ++mt) {
            const int rowh = mt * 16 + l15;
            a[mt] = *(const half8*)&h_lds[(rowh * 256 + s * 32 + quad * 8) ^ ((rowh & 7) << 3)];
        }
        #pragma unroll
        for (int ntl = 0; ntl < 3; ++ntl) {
            if (ntl < NTL) {
                const int ntg = wv + 4 * ntl;
                const half8 b = *(const half8*)(w2s + ((size_t)((s * 4 + quad) * 144) + ntg * 16 + l15) * 8);
                #pragma unroll
                for (int mt = 0; mt < 4; ++mt)
                    acc2[mt][ntl] = __builtin_amdgcn_mfma_f32_16x16x32_f16(a[mt], b, acc2[mt][ntl], 0, 0, 0);
            }
        }
    }

    // epilogue 2: stage all 129 cols in LDS f32 [64][S_OUT], then per-row
    // scatter to out[perm_s[row]*129]: 2x 256B coalesced stores + 1 dword.
    __syncthreads();                                   // all h reads done
    float* o_lds = (float*)lds_u;                      // [64][S_OUT] f32
    #pragma unroll
    for (int ntl = 0; ntl < 3; ++ntl) {
        if (ntl < NTL) {
            const int n = (wv + 4 * ntl) * 16 + l15;
            if (n < OUT_CH) {
                const float bias = b2[n];
                #pragma unroll
                for (int mt = 0; mt < 4; ++mt) {
                    #pragma unroll
                    for (int r = 0; r < 4; ++r)
                        o_lds[(mt * 16 + quad * 4 + r) * S_OUT + n] = acc2[mt][ntl][r] + bias;
                }
            }
        }
    }
    __syncthreads();
    // wave wv scatters rows wv*16 .. wv*16+15
    #pragma unroll
    for (int rr = 0; rr < 16; ++rr) {
        const int row = wv * 16 + rr;
        float* dst = out + (size_t)perm_s[row] * OUT_CH;
        const float* src = &o_lds[row * S_OUT];
        dst[lane] = src[lane];
        dst[64 + lane] = src[64 + lane];
        if (lane == 0) dst[128] = src[128];
    }
}

// ---- launch ---------------------------------------------------------------

extern "C" void kernel_launch(void* const* d_in, const int* in_sizes, int n_in,
                              void* d_out, int out_size, void* d_ws, size_t ws_size,
                              hipStream_t stream) {
    const float* xyz    = (const float*)d_in[0];
    const float* planes = (const float*)d_in[1];
    const float* lines  = (const float*)d_in[2];
    const float* w1     = (const float*)d_in[3];
    const float* b1     = (const float*)d_in[4];
    const float* w2     = (const float*)d_in[5];
    const float* b2     = (const float*)d_in[6];
    float* out = (float*)d_out;
    char* ws = (char*)d_ws;

    _Float16* w1s  = (_Float16*)(ws + OFF_W1S);
    _Float16* w2s  = (_Float16*)(ws + OFF_W2S);
    _Float16* l_t  = (_Float16*)(ws + OFF_LT);
    uint32_t* hist = (uint32_t*)(ws + OFF_HIST);
    uint32_t* cur  = (uint32_t*)(ws + OFF_CUR);
    uint32_t* perm = (uint32_t*)(ws + OFF_PERM);
    _Float16* pl_t = (_Float16*)(ws + OFF_PLT);

    const bool fast = (ws_size >= NEED_FAST);

    prep_small_k<<<NB_W1 + NB_W2 + NB_L, 256, 0, stream>>>(w1, w2, lines, w1s, w2s, l_t);

    if (fast) {
        prep_planes_k<<<(3 * GRES * GRES + 255) / 256, 256, 0, stream>>>(planes, pl_t);
        zero_k<<<NCELL / 256, 256, 0, stream>>>(hist);
        hist_k<<<NPTS / 256, 256, 0, stream>>>(xyz, hist);
        scan_k<<<1, 256, 0, stream>>>(hist, cur);
        scat_k<<<NPTS / 256, 256, 0, stream>>>(xyz, cur, perm);
        tsdf_fused40_k<1><<<NPTS / TILE_M, 256, 0, stream>>>(
            xyz, planes, lines, pl_t, l_t, w1s, w2s, b1, b2, perm, out);
    } else {
        tsdf_fused40_k<0><<<NPTS / TILE_M, 256, 0, stream>>>(
            xyz, planes, lines, pl_t, l_t, w1s, w2s, b1, b2, nullptr, out);
    }
}

// Round 9
// 524.402 us; speedup vs baseline: 1.1640x; 1.1640x over previous
//
#include <hip/hip_runtime.h>
#include <cstdint>
#include <cstddef>

// ---------------------------------------------------------------------------
// TensoSDF shape renderer: tri-plane sample + embed -> MLP(129->256->129)
// R10: revert Morton sort (R9: FETCH 352->156MB but dur -2% -> kernel is NOT
// fetch-bound; sort cost +118us). Occupancy re-run with fixed prerequisites:
// HW VGPR steps at 64/128/256 (m69) -> R6..R9's VGPR 72-84 burned a whole
// residency step (3 blocks/CU). bounds(256,4) empirically lands VGPR=64;
// LDS union trimmed to exactly 32KB (R6 epilogue: stage [64][128] f32, col
// 128 direct, coalesced burst -> WRITE was exactly nominal) -> 5 blocks/CU.
// R8's 6-load task-split gather fits 64 VGPRs (unlike R5's 30-load one).
// Keeps: NCP=40 padded planes/lines, task-split coalesced gather, N-slice
// layer-2, k-permuted w1/w2, LDS union, softplus via exp/log.
// ---------------------------------------------------------------------------

using half2v  = __attribute__((ext_vector_type(2))) _Float16;
using half4   = __attribute__((ext_vector_type(4))) _Float16;
using half8   = __attribute__((ext_vector_type(8))) _Float16;
using floatx4 = __attribute__((ext_vector_type(4))) float;

#define NPTS    524288
#define GRES    300
#define NCOMP   36
#define NCP     40
#define SDFD    256
#define IN_CH   129
#define OUT_CH  129
#define TILE_M  64
#define S_INL   168     // mlp_in LDS stride in halfs

// workspace layout (bytes), all 16B aligned
#define OFF_W1S 0
#define SZ_W1S  (5*4*256*8*2)               // 81920 : w1 swizzled f16
#define OFF_W2S (OFF_W1S + SZ_W1S)
#define SZ_W2S  (8*4*144*8*2)               // 73728 : w2 swizzled f16
#define OFF_LT  (OFF_W2S + SZ_W2S)
#define SZ_LT   (3*GRES*NCP*2)              // 72000 : lines ch-last padded f16
#define OFF_PLT (OFF_LT + SZ_LT)
#define SZ_PLT  ((size_t)3*GRES*GRES*NCP*2) // 21.6MB: planes ch-last padded f16
#define NEED_FAST ((size_t)OFF_PLT + SZ_PLT)

// ---- prep kernels ---------------------------------------------------------

__global__ void prep_planes_k(const float* __restrict__ planes, _Float16* __restrict__ pl_t) {
    int idx = blockIdx.x * 256 + threadIdx.x;           // (m*300+y)*300+x
    if (idx >= 3 * GRES * GRES) return;
    int x = idx % GRES; int t = idx / GRES; int y = t % GRES; int m = t / GRES;
    _Float16* dst = pl_t + (size_t)idx * NCP;
    const float* src = planes + (size_t)m * NCOMP * GRES * GRES + (size_t)y * GRES + x;
    #pragma unroll
    for (int j = 0; j < 5; ++j) {
        half8 o;
        #pragma unroll
        for (int e = 0; e < 8; ++e) {
            int c = j * 8 + e;
            o[e] = (c < NCOMP) ? (_Float16)src[(size_t)c * GRES * GRES] : (_Float16)0.f;
        }
        *(half8*)(dst + j * 8) = o;
    }
}

#define NB_W1 ((5*4*256*8 + 255)/256)      // 160
#define NB_W2 ((8*4*144*8 + 255)/256)      // 144
#define NB_L  ((3*GRES + 255)/256)         // 4
__global__ void prep_small_k(const float* __restrict__ w1, const float* __restrict__ w2,
                             const float* __restrict__ lines,
                             _Float16* __restrict__ w1s, _Float16* __restrict__ w2s,
                             _Float16* __restrict__ l_t) {
    int b = blockIdx.x;
    if (b < NB_W1) {
        int t = b * 256 + threadIdx.x;                   // < 40960 exactly
        int j = t & 7; int n = (t >> 3) & 255; int q = t >> 11;
        int k = q * 8 + j;                               // 0..159
        float v = 0.f;
        if (k < 120) {
            int m = k / 40, c = k % 40;
            if (c < NCOMP) v = w1[n * IN_CH + 21 + m * NCOMP + c];
        } else if (k < 141) {
            v = w1[n * IN_CH + (k - 120)];
        }
        w1s[t] = (_Float16)v;
    } else if (b < NB_W1 + NB_W2) {
        int t = (b - NB_W1) * 256 + threadIdx.x;
        if (t >= 8*4*144*8) return;
        int j = t & 7; int r = t >> 3; int n = r % 144; int q = r / 144;
        int k = q * 8 + j;                               // 0..255
        float v = (n < OUT_CH) ? w2[n * SDFD + k] : 0.f;
        w2s[t] = (_Float16)v;
    } else {
        int idx = (b - NB_W1 - NB_W2) * 256 + threadIdx.x;   // m*300+z
        if (idx >= 3 * GRES) return;
        int z = idx % GRES; int m = idx / GRES;
        _Float16* dst = l_t + (size_t)idx * NCP;
        const float* src = lines + ((size_t)m * NCOMP) * GRES + z;
        #pragma unroll
        for (int c = 0; c < NCOMP; ++c) dst[c] = (_Float16)src[(size_t)c * GRES];
        dst[36] = dst[37] = dst[38] = dst[39] = (_Float16)0.f;
    }
}

// ---- device helpers -------------------------------------------------------

__device__ __forceinline__ float softplus100(float z) {
    return fmaxf(z, 0.f) + __logf(1.f + __expf(-fabsf(z)));
}

__device__ __forceinline__ void plane_coords(int m, float X, float Y, float Z,
                                             int& x0, int& y0, int& z0,
                                             float& tx, float& ty, float& tz) {
    const float px = (m == 2) ? Y : X;
    const float py = (m == 0) ? Y : Z;
    const float pz = (m == 0) ? Z : ((m == 1) ? Y : X);
    float fx = (px + 1.f) * 0.5f * 299.f;
    float fy = (py + 1.f) * 0.5f * 299.f;
    float fz = (pz + 1.f) * 0.5f * 299.f;
    x0 = (int)floorf(fx); x0 = x0 < 0 ? 0 : (x0 > 298 ? 298 : x0);
    y0 = (int)floorf(fy); y0 = y0 < 0 ? 0 : (y0 > 298 ? 298 : y0);
    z0 = (int)floorf(fz); z0 = z0 < 0 ? 0 : (z0 > 298 ? 298 : z0);
    tx = fx - (float)x0; ty = fy - (float)y0; tz = fz - (float)z0;
}

// embed -> chunks c16=15..19 (k=120..159); zeros beyond k=140
__device__ __forceinline__ void embed_chunks(float X, float Y, float Z, half8 e[5]) {
    const float v3[3] = {X, Y, Z};
    _Float16 s[3][3], c[3][3];
    #pragma unroll
    for (int d = 0; d < 3; ++d) {
        float fm = 1.f;
        #pragma unroll
        for (int q = 0; q < 3; ++q) {
            const float a = v3[d] * fm;
            s[d][q] = (_Float16)__sinf(a);
            c[d][q] = (_Float16)__cosf(a);
            fm *= 2.f;
        }
    }
    const _Float16 z0 = (_Float16)0.f;
    e[0] = (half8){(_Float16)X, (_Float16)Y, (_Float16)Z, s[0][0], s[0][1], s[0][2], s[1][0], s[1][1]};
    e[1] = (half8){s[1][2], s[2][0], s[2][1], s[2][2], c[0][0], c[0][1], c[0][2], c[1][0]};
    e[2] = (half8){c[1][1], c[1][2], c[2][0], c[2][1], c[2][2], z0, z0, z0};
    e[3] = (half8){z0,z0,z0,z0,z0,z0,z0,z0};
    e[4] = (half8){z0,z0,z0,z0,z0,z0,z0,z0};
}

__device__ __forceinline__ half8 splat8(_Float16 v) {
    return (half8){v, v, v, v, v, v, v, v};
}

// ---- fused kernel ---------------------------------------------------------
// LDS: single 32768B union buffer, three lifetimes:
//   A (phase1/layer1): mlp_in [64][S_INL=168] f16, 21504B
//   B (epilogue1/layer2): h [64][256] f16 XOR-swz (row&7)<<3, 32768B
//   C (epilogue2): out stage [64][128] f32, 32768B (col 128 direct)
// bounds(256,4): empirically VGPR=64 -> HW step admits 8 waves/SIMD;
// LDS binds at 5 blocks/CU (163840/32768), 20 waves/CU.

template <int FASTMODE>
__global__ __launch_bounds__(256, 4)
void tsdf_fused40_k(const float* __restrict__ xyz,
                    const float* __restrict__ planes, const float* __restrict__ lines,
                    const _Float16* __restrict__ pl_t, const _Float16* __restrict__ l_t,
                    const _Float16* __restrict__ w1s, const _Float16* __restrict__ w2s,
                    const float* __restrict__ b1, const float* __restrict__ b2,
                    float* __restrict__ out)
{
    __shared__ _Float16 lds_u[TILE_M * 256];           // 32768 B union
    _Float16* mlp_lds = lds_u;                         // [64][S_INL]
    _Float16* h_lds   = lds_u;                         // [64][256] swz
    const int tid = threadIdx.x, blk = blockIdx.x;

    // ---------------- phase 1: sampling + embed into LDS -------------------
    {
        const int task = tid & 15;                     // 0..14 gather, 15 embed
        const int pb4  = (tid >> 4) * 4;               // first of 4 points
        const int m    = task / 5;                     // plane (3 if embed)
        const int j    = task - m * 5;                 // chunk within plane
        const float* xb = xyz + ((size_t)blk * TILE_M + pb4) * 3;
        const floatx4 xv0 = *(const floatx4*)(xb);
        const floatx4 xv1 = *(const floatx4*)(xb + 4);
        const floatx4 xv2 = *(const floatx4*)(xb + 8);
        #pragma unroll
        for (int g = 0; g < 4; ++g) {
            const int p = pb4 + g;
            const float X = (g == 0) ? xv0[0] : (g == 1) ? xv0[3] : (g == 2) ? xv1[2] : xv2[1];
            const float Y = (g == 0) ? xv0[1] : (g == 1) ? xv1[0] : (g == 2) ? xv1[3] : xv2[2];
            const float Z = (g == 0) ? xv0[2] : (g == 1) ? xv1[1] : (g == 2) ? xv2[0] : xv2[3];
            if (task < 15) {
                int x0, y0, z0; float tx, ty, tz;
                plane_coords(m, X, Y, Z, x0, y0, z0, tx, ty, tz);
                if (FASTMODE) {
                    const half8 W00 = splat8((_Float16)((1.f - tx) * (1.f - ty)));
                    const half8 W01 = splat8((_Float16)(tx * (1.f - ty)));
                    const half8 W10 = splat8((_Float16)((1.f - tx) * ty));
                    const half8 W11 = splat8((_Float16)(tx * ty));
                    const half8 WL0 = splat8((_Float16)(1.f - tz));
                    const half8 WL1 = splat8((_Float16)tz);
                    const _Float16* r0 = pl_t + ((size_t)(m * GRES + y0) * GRES + x0) * NCP + 8 * j;
                    const _Float16* r1 = r0 + (size_t)GRES * NCP;
                    const _Float16* lb = l_t + (size_t)(m * GRES + z0) * NCP + 8 * j;
                    const half8 v00 = *(const half8*)(r0);
                    const half8 v01 = *(const half8*)(r0 + NCP);
                    const half8 v10 = *(const half8*)(r1);
                    const half8 v11 = *(const half8*)(r1 + NCP);
                    const half8 l0  = *(const half8*)(lb);
                    const half8 l1  = *(const half8*)(lb + NCP);
                    const half8 pf = v00 * W00 + v01 * W01 + v10 * W10 + v11 * W11;
                    const half8 lf = l0 * WL0 + l1 * WL1;
                    *(half8*)&mlp_lds[p * S_INL + task * 8] = pf * lf;
                } else {
                    const float w00 = (1.f - tx) * (1.f - ty), w01 = tx * (1.f - ty);
                    const float w10 = (1.f - tx) * ty,         w11 = tx * ty;
                    const float lw0 = 1.f - tz, lw1 = tz;
                    half8 f;
                    #pragma unroll
                    for (int e = 0; e < 8; ++e) {
                        const int c = j * 8 + e;
                        float v = 0.f;
                        if (c < NCOMP) {
                            const float* pc = planes + ((size_t)(m * NCOMP + c) * GRES + y0) * GRES + x0;
                            const float* lc = lines + ((size_t)m * NCOMP + c) * GRES + z0;
                            const float pfv = pc[0] * w00 + pc[1] * w01 + pc[GRES] * w10 + pc[GRES + 1] * w11;
                            v = pfv * (lc[0] * lw0 + lc[1] * lw1);
                        }
                        f[e] = (_Float16)v;
                    }
                    *(half8*)&mlp_lds[p * S_INL + task * 8] = f;
                }
            } else {
                half8 e[5];
                embed_chunks(X, Y, Z, e);
                #pragma unroll
                for (int jj = 0; jj < 5; ++jj)
                    *(half8*)&mlp_lds[p * S_INL + (15 + jj) * 8] = e[jj];
            }
        }
    }
    __syncthreads();

    const int lane = tid & 63, wv = tid >> 6, l15 = lane & 15, quad = lane >> 4;

    // ---------------- layer 1: [64x160] @ [160x256] -> h -------------------
    floatx4 acc1[4][4];
    #pragma unroll
    for (int mt = 0; mt < 4; ++mt)
        #pragma unroll
        for (int nt = 0; nt < 4; ++nt)
            acc1[mt][nt] = (floatx4){0.f, 0.f, 0.f, 0.f};

    #pragma unroll
    for (int s = 0; s < 5; ++s) {
        half8 a[4], b[4];
        #pragma unroll
        for (int mt = 0; mt < 4; ++mt)
            a[mt] = *(const half8*)&mlp_lds[(mt * 16 + l15) * S_INL + s * 32 + quad * 8];
        #pragma unroll
        for (int nt = 0; nt < 4; ++nt)
            b[nt] = *(const half8*)(w1s + ((size_t)((s * 4 + quad) * 256) + wv * 64 + nt * 16 + l15) * 8);
        #pragma unroll
        for (int mt = 0; mt < 4; ++mt)
            #pragma unroll
            for (int nt = 0; nt < 4; ++nt)
                acc1[mt][nt] = __builtin_amdgcn_mfma_f32_16x16x32_f16(a[mt], b[nt], acc1[mt][nt], 0, 0, 0);
    }
    __syncthreads();   // mlp_lds reads done; union -> h

    // epilogue 1: softplus(100z)/100, write h (f16) to swizzled LDS
    #pragma unroll
    for (int nt = 0; nt < 4; ++nt) {
        const int n = wv * 64 + nt * 16 + l15;
        const float bias = b1[n];
        #pragma unroll
        for (int mt = 0; mt < 4; ++mt) {
            #pragma unroll
            for (int r = 0; r < 4; ++r) {
                const int rowh = mt * 16 + quad * 4 + r;
                const float z = 100.f * (acc1[mt][nt][r] + bias);
                h_lds[(rowh * 256 + n) ^ ((rowh & 7) << 3)] = (_Float16)(softplus100(z) * 0.01f);
            }
        }
    }
    __syncthreads();

    // ---------------- layer 2: [64x256] @ [256x144] -> out -----------------
    // N-slice ownership: wave w owns col-tiles {w, w+4, (8 for w==0)};
    // w2s read once per block (72KB).
    const int NTL = (wv == 0) ? 3 : 2;
    floatx4 acc2[4][3];
    #pragma unroll
    for (int mt = 0; mt < 4; ++mt)
        #pragma unroll
        for (int ntl = 0; ntl < 3; ++ntl)
            acc2[mt][ntl] = (floatx4){0.f, 0.f, 0.f, 0.f};

    #pragma unroll
    for (int s = 0; s < 8; ++s) {
        half8 a[4];
        #pragma unroll
        for (int mt = 0; mt < 4; ++mt) {
            const int rowh = mt * 16 + l15;
            a[mt] = *(const half8*)&h_lds[(rowh * 256 + s * 32 + quad * 8) ^ ((rowh & 7) << 3)];
        }
        #pragma unroll
        for (int ntl = 0; ntl < 3; ++ntl) {
            if (ntl < NTL) {
                const int ntg = wv + 4 * ntl;
                const half8 b = *(const half8*)(w2s + ((size_t)((s * 4 + quad) * 144) + ntg * 16 + l15) * 8);
                #pragma unroll
                for (int mt = 0; mt < 4; ++mt)
                    acc2[mt][ntl] = __builtin_amdgcn_mfma_f32_16x16x32_f16(a[mt], b, acc2[mt][ntl], 0, 0, 0);
            }
        }
    }

    // epilogue 2: stage cols 0..127 in LDS f32 [64][128] (=32KB, reuses dead
    // union), col 128 stored direct; then burst-copy 8192 dwords coalesced
    // (proven exactly-nominal WRITE in R6).
    __syncthreads();                                   // all h reads done
    float* o_lds = (float*)lds_u;                      // [64][128] f32
    const size_t obase = (size_t)blk * TILE_M;
    #pragma unroll
    for (int ntl = 0; ntl < 3; ++ntl) {
        if (ntl < NTL) {
            const int n = (wv + 4 * ntl) * 16 + l15;
            if (n < 128) {
                const float bias = b2[n];
                #pragma unroll
                for (int mt = 0; mt < 4; ++mt) {
                    #pragma unroll
                    for (int r = 0; r < 4; ++r)
                        o_lds[(mt * 16 + quad * 4 + r) * 128 + n] = acc2[mt][ntl][r] + bias;
                }
            } else if (n == 128) {
                const float bias = b2[128];
                #pragma unroll
                for (int mt = 0; mt < 4; ++mt) {
                    #pragma unroll
                    for (int r = 0; r < 4; ++r)
                        out[(obase + mt * 16 + quad * 4 + r) * OUT_CH + 128] = acc2[mt][ntl][r] + bias;
                }
            }
        }
    }
    __syncthreads();
    #pragma unroll
    for (int c = 0; c < 32; ++c) {
        const int idx = c * 256 + tid;                 // 0..8191
        const int row = idx >> 7, col = idx & 127;
        out[(obase + row) * OUT_CH + col] = o_lds[idx];
    }
}

// ---- launch ---------------------------------------------------------------

extern "C" void kernel_launch(void* const* d_in, const int* in_sizes, int n_in,
                              void* d_out, int out_size, void* d_ws, size_t ws_size,
                              hipStream_t stream) {
    const float* xyz    = (const float*)d_in[0];
    const float* planes = (const float*)d_in[1];
    const float* lines  = (const float*)d_in[2];
    const float* w1     = (const float*)d_in[3];
    const float* b1     = (const float*)d_in[4];
    const float* w2     = (const float*)d_in[5];
    const float* b2     = (const float*)d_in[6];
    float* out = (float*)d_out;
    char* ws = (char*)d_ws;

    _Float16* w1s  = (_Float16*)(ws + OFF_W1S);
    _Float16* w2s  = (_Float16*)(ws + OFF_W2S);
    _Float16* l_t  = (_Float16*)(ws + OFF_LT);
    _Float16* pl_t = (_Float16*)(ws + OFF_PLT);

    const bool fast = (ws_size >= NEED_FAST);

    prep_small_k<<<NB_W1 + NB_W2 + NB_L, 256, 0, stream>>>(w1, w2, lines, w1s, w2s, l_t);

    if (fast) {
        prep_planes_k<<<(3 * GRES * GRES + 255) / 256, 256, 0, stream>>>(planes, pl_t);
        tsdf_fused40_k<1><<<NPTS / TILE_M, 256, 0, stream>>>(
            xyz, planes, lines, pl_t, l_t, w1s, w2s, b1, b2, out);
    } else {
        tsdf_fused40_k<0><<<NPTS / TILE_M, 256, 0, stream>>>(
            xyz, planes, lines, pl_t, l_t, w1s, w2s, b1, b2, out);
    }
}

// Round 10
// 504.441 us; speedup vs baseline: 1.2101x; 1.0396x over previous
//
#include <hip/hip_runtime.h>
#include <cstdint>
#include <cstddef>

// ---------------------------------------------------------------------------
// TensoSDF shape renderer: tri-plane sample + embed -> MLP(129->256->129)
// R11: operand-swapped MFMA (D transposed) -> packed LDS epilogues.
//  R10 post-mortem: VALUBusy 60% dominant; epilogue-1 was 64 scalar
//  ds_write_b16/thread (column-stride h writes), epilogue-2 scalar dwords +
//  col-128 scattered stores re-introduced RMW (WRITE 371MB, FETCH 426MB).
//  - Swap A/B in both layers (fragments are symmetric): thread then holds
//    4 consecutive n at fixed m -> epilogue-1 = 16x ds_write_b64 (half4),
//    epilogue-2 staging = float4 b128 writes, biases load as float4.
//  - Epilogue-2 two-pass [32][132] f32 stage INCLUDING col 128; each pass
//    bursts 4128 contiguous dwords -> block's 33KB written fully
//    sequentially, no partial-line RMW.
// Keeps: R10 bounds(256,4)/VGPR=64/32KB LDS union, NCP=40 16B gathers,
//  task-split phase 1, N-slice layer-2, k-permuted w1/w2.
// ---------------------------------------------------------------------------

using half2v  = __attribute__((ext_vector_type(2))) _Float16;
using half4   = __attribute__((ext_vector_type(4))) _Float16;
using half8   = __attribute__((ext_vector_type(8))) _Float16;
using floatx4 = __attribute__((ext_vector_type(4))) float;

#define NPTS    524288
#define GRES    300
#define NCOMP   36
#define NCP     40
#define SDFD    256
#define IN_CH   129
#define OUT_CH  129
#define TILE_M  64
#define S_INL   168     // mlp_in LDS stride in halfs
#define S_O2    132     // out-stage stride in floats (two-pass [32][132])

// workspace layout (bytes), all 16B aligned
#define OFF_W1S 0
#define SZ_W1S  (5*4*256*8*2)               // 81920 : w1 swizzled f16
#define OFF_W2S (OFF_W1S + SZ_W1S)
#define SZ_W2S  (8*4*144*8*2)               // 73728 : w2 swizzled f16
#define OFF_LT  (OFF_W2S + SZ_W2S)
#define SZ_LT   (3*GRES*NCP*2)              // 72000 : lines ch-last padded f16
#define OFF_PLT (OFF_LT + SZ_LT)
#define SZ_PLT  ((size_t)3*GRES*GRES*NCP*2) // 21.6MB: planes ch-last padded f16
#define NEED_FAST ((size_t)OFF_PLT + SZ_PLT)

// ---- prep kernels ---------------------------------------------------------

__global__ void prep_planes_k(const float* __restrict__ planes, _Float16* __restrict__ pl_t) {
    int idx = blockIdx.x * 256 + threadIdx.x;           // (m*300+y)*300+x
    if (idx >= 3 * GRES * GRES) return;
    int x = idx % GRES; int t = idx / GRES; int y = t % GRES; int m = t / GRES;
    _Float16* dst = pl_t + (size_t)idx * NCP;
    const float* src = planes + (size_t)m * NCOMP * GRES * GRES + (size_t)y * GRES + x;
    #pragma unroll
    for (int j = 0; j < 5; ++j) {
        half8 o;
        #pragma unroll
        for (int e = 0; e < 8; ++e) {
            int c = j * 8 + e;
            o[e] = (c < NCOMP) ? (_Float16)src[(size_t)c * GRES * GRES] : (_Float16)0.f;
        }
        *(half8*)(dst + j * 8) = o;
    }
}

#define NB_W1 ((5*4*256*8 + 255)/256)      // 160
#define NB_W2 ((8*4*144*8 + 255)/256)      // 144
#define NB_L  ((3*GRES + 255)/256)         // 4
__global__ void prep_small_k(const float* __restrict__ w1, const float* __restrict__ w2,
                             const float* __restrict__ lines,
                             _Float16* __restrict__ w1s, _Float16* __restrict__ w2s,
                             _Float16* __restrict__ l_t) {
    int b = blockIdx.x;
    if (b < NB_W1) {
        int t = b * 256 + threadIdx.x;                   // < 40960 exactly
        int j = t & 7; int n = (t >> 3) & 255; int q = t >> 11;
        int k = q * 8 + j;                               // 0..159
        float v = 0.f;
        if (k < 120) {
            int m = k / 40, c = k % 40;
            if (c < NCOMP) v = w1[n * IN_CH + 21 + m * NCOMP + c];
        } else if (k < 141) {
            v = w1[n * IN_CH + (k - 120)];
        }
        w1s[t] = (_Float16)v;
    } else if (b < NB_W1 + NB_W2) {
        int t = (b - NB_W1) * 256 + threadIdx.x;
        if (t >= 8*4*144*8) return;
        int j = t & 7; int r = t >> 3; int n = r % 144; int q = r / 144;
        int k = q * 8 + j;                               // 0..255
        float v = (n < OUT_CH) ? w2[n * SDFD + k] : 0.f;
        w2s[t] = (_Float16)v;
    } else {
        int idx = (b - NB_W1 - NB_W2) * 256 + threadIdx.x;   // m*300+z
        if (idx >= 3 * GRES) return;
        int z = idx % GRES; int m = idx / GRES;
        _Float16* dst = l_t + (size_t)idx * NCP;
        const float* src = lines + ((size_t)m * NCOMP) * GRES + z;
        #pragma unroll
        for (int c = 0; c < NCOMP; ++c) dst[c] = (_Float16)src[(size_t)c * GRES];
        dst[36] = dst[37] = dst[38] = dst[39] = (_Float16)0.f;
    }
}

// ---- device helpers -------------------------------------------------------

__device__ __forceinline__ float softplus100(float z) {
    return fmaxf(z, 0.f) + __logf(1.f + __expf(-fabsf(z)));
}

__device__ __forceinline__ void plane_coords(int m, float X, float Y, float Z,
                                             int& x0, int& y0, int& z0,
                                             float& tx, float& ty, float& tz) {
    const float px = (m == 2) ? Y : X;
    const float py = (m == 0) ? Y : Z;
    const float pz = (m == 0) ? Z : ((m == 1) ? Y : X);
    float fx = (px + 1.f) * 0.5f * 299.f;
    float fy = (py + 1.f) * 0.5f * 299.f;
    float fz = (pz + 1.f) * 0.5f * 299.f;
    x0 = (int)floorf(fx); x0 = x0 < 0 ? 0 : (x0 > 298 ? 298 : x0);
    y0 = (int)floorf(fy); y0 = y0 < 0 ? 0 : (y0 > 298 ? 298 : y0);
    z0 = (int)floorf(fz); z0 = z0 < 0 ? 0 : (z0 > 298 ? 298 : z0);
    tx = fx - (float)x0; ty = fy - (float)y0; tz = fz - (float)z0;
}

// embed -> chunks c16=15..19 (k=120..159); zeros beyond k=140
__device__ __forceinline__ void embed_chunks(float X, float Y, float Z, half8 e[5]) {
    const float v3[3] = {X, Y, Z};
    _Float16 s[3][3], c[3][3];
    #pragma unroll
    for (int d = 0; d < 3; ++d) {
        float fm = 1.f;
        #pragma unroll
        for (int q = 0; q < 3; ++q) {
            const float a = v3[d] * fm;
            s[d][q] = (_Float16)__sinf(a);
            c[d][q] = (_Float16)__cosf(a);
            fm *= 2.f;
        }
    }
    const _Float16 z0 = (_Float16)0.f;
    e[0] = (half8){(_Float16)X, (_Float16)Y, (_Float16)Z, s[0][0], s[0][1], s[0][2], s[1][0], s[1][1]};
    e[1] = (half8){s[1][2], s[2][0], s[2][1], s[2][2], c[0][0], c[0][1], c[0][2], c[1][0]};
    e[2] = (half8){c[1][1], c[1][2], c[2][0], c[2][1], c[2][2], z0, z0, z0};
    e[3] = (half8){z0,z0,z0,z0,z0,z0,z0,z0};
    e[4] = (half8){z0,z0,z0,z0,z0,z0,z0,z0};
}

__device__ __forceinline__ half8 splat8(_Float16 v) {
    return (half8){v, v, v, v, v, v, v, v};
}

// ---- fused kernel ---------------------------------------------------------
// LDS: single 32768B union buffer, three lifetimes:
//   A (phase1/layer1): mlp_in [64][S_INL=168] f16, 21504B
//   B (epilogue1/layer2): h [64][256] f16 XOR-swz (row&7)<<3, 32768B
//   C (epilogue2, x2 passes): out stage [32][S_O2=132] f32, 16896B
// Both MFMA layers operand-swapped: D rows = N, cols = M (lane l15 = m,
// quad*4+r = 4 consecutive n) -> packed LDS writes everywhere.

template <int FASTMODE>
__global__ __launch_bounds__(256, 4)
void tsdf_fused40_k(const float* __restrict__ xyz,
                    const float* __restrict__ planes, const float* __restrict__ lines,
                    const _Float16* __restrict__ pl_t, const _Float16* __restrict__ l_t,
                    const _Float16* __restrict__ w1s, const _Float16* __restrict__ w2s,
                    const float* __restrict__ b1, const float* __restrict__ b2,
                    float* __restrict__ out)
{
    __shared__ _Float16 lds_u[TILE_M * 256];           // 32768 B union
    _Float16* mlp_lds = lds_u;                         // [64][S_INL]
    _Float16* h_lds   = lds_u;                         // [64][256] swz
    const int tid = threadIdx.x, blk = blockIdx.x;

    // ---------------- phase 1: sampling + embed into LDS -------------------
    {
        const int task = tid & 15;                     // 0..14 gather, 15 embed
        const int pb4  = (tid >> 4) * 4;               // first of 4 points
        const int m    = task / 5;                     // plane (3 if embed)
        const int j    = task - m * 5;                 // chunk within plane
        const float* xb = xyz + ((size_t)blk * TILE_M + pb4) * 3;
        const floatx4 xv0 = *(const floatx4*)(xb);
        const floatx4 xv1 = *(const floatx4*)(xb + 4);
        const floatx4 xv2 = *(const floatx4*)(xb + 8);
        #pragma unroll
        for (int g = 0; g < 4; ++g) {
            const int p = pb4 + g;
            const float X = (g == 0) ? xv0[0] : (g == 1) ? xv0[3] : (g == 2) ? xv1[2] : xv2[1];
            const float Y = (g == 0) ? xv0[1] : (g == 1) ? xv1[0] : (g == 2) ? xv1[3] : xv2[2];
            const float Z = (g == 0) ? xv0[2] : (g == 1) ? xv1[1] : (g == 2) ? xv2[0] : xv2[3];
            if (task < 15) {
                int x0, y0, z0; float tx, ty, tz;
                plane_coords(m, X, Y, Z, x0, y0, z0, tx, ty, tz);
                if (FASTMODE) {
                    const half8 W00 = splat8((_Float16)((1.f - tx) * (1.f - ty)));
                    const half8 W01 = splat8((_Float16)(tx * (1.f - ty)));
                    const half8 W10 = splat8((_Float16)((1.f - tx) * ty));
                    const half8 W11 = splat8((_Float16)(tx * ty));
                    const half8 WL0 = splat8((_Float16)(1.f - tz));
                    const half8 WL1 = splat8((_Float16)tz);
                    const _Float16* r0 = pl_t + ((size_t)(m * GRES + y0) * GRES + x0) * NCP + 8 * j;
                    const _Float16* r1 = r0 + (size_t)GRES * NCP;
                    const _Float16* lb = l_t + (size_t)(m * GRES + z0) * NCP + 8 * j;
                    const half8 v00 = *(const half8*)(r0);
                    const half8 v01 = *(const half8*)(r0 + NCP);
                    const half8 v10 = *(const half8*)(r1);
                    const half8 v11 = *(const half8*)(r1 + NCP);
                    const half8 l0  = *(const half8*)(lb);
                    const half8 l1  = *(const half8*)(lb + NCP);
                    const half8 pf = v00 * W00 + v01 * W01 + v10 * W10 + v11 * W11;
                    const half8 lf = l0 * WL0 + l1 * WL1;
                    *(half8*)&mlp_lds[p * S_INL + task * 8] = pf * lf;
                } else {
                    const float w00 = (1.f - tx) * (1.f - ty), w01 = tx * (1.f - ty);
                    const float w10 = (1.f - tx) * ty,         w11 = tx * ty;
                    const float lw0 = 1.f - tz, lw1 = tz;
                    half8 f;
                    #pragma unroll
                    for (int e = 0; e < 8; ++e) {
                        const int c = j * 8 + e;
                        float v = 0.f;
                        if (c < NCOMP) {
                            const float* pc = planes + ((size_t)(m * NCOMP + c) * GRES + y0) * GRES + x0;
                            const float* lc = lines + ((size_t)m * NCOMP + c) * GRES + z0;
                            const float pfv = pc[0] * w00 + pc[1] * w01 + pc[GRES] * w10 + pc[GRES + 1] * w11;
                            v = pfv * (lc[0] * lw0 + lc[1] * lw1);
                        }
                        f[e] = (_Float16)v;
                    }
                    *(half8*)&mlp_lds[p * S_INL + task * 8] = f;
                }
            } else {
                half8 e[5];
                embed_chunks(X, Y, Z, e);
                #pragma unroll
                for (int jj = 0; jj < 5; ++jj)
                    *(half8*)&mlp_lds[p * S_INL + (15 + jj) * 8] = e[jj];
            }
        }
    }
    __syncthreads();

    const int lane = tid & 63, wv = tid >> 6, l15 = lane & 15, quad = lane >> 4;

    // ---------------- layer 1 (swapped): D[n][m] -------------------------
    // acc1[nt][mt]: rows n = wv*64+nt*16+quad*4+r, cols m = mt*16+l15
    floatx4 acc1[4][4];
    #pragma unroll
    for (int nt = 0; nt < 4; ++nt)
        #pragma unroll
        for (int mt = 0; mt < 4; ++mt)
            acc1[nt][mt] = (floatx4){0.f, 0.f, 0.f, 0.f};

    #pragma unroll
    for (int s = 0; s < 5; ++s) {
        half8 aw[4], bm[4];
        #pragma unroll
        for (int nt = 0; nt < 4; ++nt)
            aw[nt] = *(const half8*)(w1s + ((size_t)((s * 4 + quad) * 256) + wv * 64 + nt * 16 + l15) * 8);
        #pragma unroll
        for (int mt = 0; mt < 4; ++mt)
            bm[mt] = *(const half8*)&mlp_lds[(mt * 16 + l15) * S_INL + s * 32 + quad * 8];
        #pragma unroll
        for (int nt = 0; nt < 4; ++nt)
            #pragma unroll
            for (int mt = 0; mt < 4; ++mt)
                acc1[nt][mt] = __builtin_amdgcn_mfma_f32_16x16x32_f16(aw[nt], bm[mt], acc1[nt][mt], 0, 0, 0);
    }
    __syncthreads();   // mlp_lds reads done; union -> h

    // epilogue 1: softplus, PACKED half4 writes: h[m][n0..n0+3]
    #pragma unroll
    for (int nt = 0; nt < 4; ++nt) {
        const int n0 = wv * 64 + nt * 16 + quad * 4;
        const floatx4 b4 = *(const floatx4*)&b1[n0];
        #pragma unroll
        for (int mt = 0; mt < 4; ++mt) {
            const int m = mt * 16 + l15;
            half4 hv;
            #pragma unroll
            for (int r = 0; r < 4; ++r) {
                const float z = 100.f * (acc1[nt][mt][r] + b4[r]);
                hv[r] = (_Float16)(softplus100(z) * 0.01f);
            }
            const int idx = (m * 256 + n0) ^ ((m & 7) << 3);
            *(half4*)&h_lds[idx] = hv;
        }
    }
    __syncthreads();

    // ---------------- layer 2 (swapped): D[n][m] -------------------------
    // N-slice: wave w owns col-tiles ntg = {w, w+4, (8 for w==0)}.
    // acc2[mt][ntl]: rows n = ntg*16+quad*4+r, cols m = mt*16+l15
    const int NTL = (wv == 0) ? 3 : 2;
    floatx4 acc2[4][3];
    #pragma unroll
    for (int mt = 0; mt < 4; ++mt)
        #pragma unroll
        for (int ntl = 0; ntl < 3; ++ntl)
            acc2[mt][ntl] = (floatx4){0.f, 0.f, 0.f, 0.f};

    #pragma unroll
    for (int s = 0; s < 8; ++s) {
        half8 bh[4];
        #pragma unroll
        for (int mt = 0; mt < 4; ++mt) {
            const int rowh = mt * 16 + l15;
            bh[mt] = *(const half8*)&h_lds[(rowh * 256 + s * 32 + quad * 8) ^ ((rowh & 7) << 3)];
        }
        #pragma unroll
        for (int ntl = 0; ntl < 3; ++ntl) {
            if (ntl < NTL) {
                const int ntg = wv + 4 * ntl;
                const half8 aw = *(const half8*)(w2s + ((size_t)((s * 4 + quad) * 144) + ntg * 16 + l15) * 8);
                #pragma unroll
                for (int mt = 0; mt < 4; ++mt)
                    acc2[mt][ntl] = __builtin_amdgcn_mfma_f32_16x16x32_f16(aw, bh[mt], acc2[mt][ntl], 0, 0, 0);
            }
        }
    }

    // epilogue 2: two passes of 32 rows; stage [32][S_O2] f32 incl col 128,
    // float4 packed writes, then burst 4128 contiguous dwords per pass.
    float* o_lds = (float*)lds_u;                      // [32][S_O2]
    const size_t obase = (size_t)blk * TILE_M;
    #pragma unroll
    for (int hp = 0; hp < 2; ++hp) {
        __syncthreads();                               // h reads / prev burst done
        #pragma unroll
        for (int mt = hp * 2; mt < hp * 2 + 2; ++mt) {
            const int mrow = mt * 16 + l15 - hp * 32;  // 0..31
            #pragma unroll
            for (int ntl = 0; ntl < 3; ++ntl) {
                if (ntl < NTL) {
                    const int n0 = (wv + 4 * ntl) * 16 + quad * 4;
                    if (n0 < 128) {
                        const floatx4 b4 = *(const floatx4*)&b2[n0];
                        floatx4 v;
                        #pragma unroll
                        for (int r = 0; r < 4; ++r) v[r] = acc2[mt][ntl][r] + b4[r];
                        *(floatx4*)&o_lds[mrow * S_O2 + n0] = v;
                    } else if (n0 == 128) {
                        o_lds[mrow * S_O2 + 128] = acc2[mt][ntl][0] + b2[128];
                    }
                }
            }
        }
        __syncthreads();
        float* oh = out + (obase + hp * 32) * OUT_CH;
        #pragma unroll
        for (int c = 0; c < 17; ++c) {
            const int idx = c * 256 + tid;             // 0..4351
            if (idx < 32 * OUT_CH) {
                const int row = idx / 129;
                const int col = idx - row * 129;
                oh[idx] = o_lds[row * S_O2 + col];
            }
        }
    }
}

// ---- launch ---------------------------------------------------------------

extern "C" void kernel_launch(void* const* d_in, const int* in_sizes, int n_in,
                              void* d_out, int out_size, void* d_ws, size_t ws_size,
                              hipStream_t stream) {
    const float* xyz    = (const float*)d_in[0];
    const float* planes = (const float*)d_in[1];
    const float* lines  = (const float*)d_in[2];
    const float* w1     = (const float*)d_in[3];
    const float* b1     = (const float*)d_in[4];
    const float* w2     = (const float*)d_in[5];
    const float* b2     = (const float*)d_in[6];
    float* out = (float*)d_out;
    char* ws = (char*)d_ws;

    _Float16* w1s  = (_Float16*)(ws + OFF_W1S);
    _Float16* w2s  = (_Float16*)(ws + OFF_W2S);
    _Float16* l_t  = (_Float16*)(ws + OFF_LT);
    _Float16* pl_t = (_Float16*)(ws + OFF_PLT);

    const bool fast = (ws_size >= NEED_FAST);

    prep_small_k<<<NB_W1 + NB_W2 + NB_L, 256, 0, stream>>>(w1, w2, lines, w1s, w2s, l_t);

    if (fast) {
        prep_planes_k<<<(3 * GRES * GRES + 255) / 256, 256, 0, stream>>>(planes, pl_t);
        tsdf_fused40_k<1><<<NPTS / TILE_M, 256, 0, stream>>>(
            xyz, planes, lines, pl_t, l_t, w1s, w2s, b1, b2, out);
    } else {
        tsdf_fused40_k<0><<<NPTS / TILE_M, 256, 0, stream>>>(
            xyz, planes, lines, pl_t, l_t, w1s, w2s, b1, b2, out);
    }
}